// Round 1
// baseline (503.615 us; speedup 1.0000x reference)
//
#include <hip/hip_runtime.h>
#include <math.h>

#define BB 16
#define LL 128
#define RR 200
#define HH 768
#define VV 30522

// ---------------------------------------------------------------------------
// last-occurrence flags: flag[b*R+r] = 1 iff no r' > r has the same token id
// (numpy fancy assignment semantics: last write wins)
// ---------------------------------------------------------------------------
__global__ void last_occurrence_kernel(const int* __restrict__ ids,
                                       unsigned char* __restrict__ flag) {
    int i = blockIdx.x * 256 + threadIdx.x;   // i = b*RR + r
    if (i >= BB * RR) return;
    int b = i / RR;
    int r = i - b * RR;
    int id = ids[i];
    unsigned char ok = 1;
    for (int r2 = r + 1; r2 < RR; ++r2) {
        if (ids[b * RR + r2] == id) { ok = 0; break; }
    }
    flag[i] = ok;
}

// ---------------------------------------------------------------------------
// C[M,768] = A[M,768] @ W[768,768] + bias   (fp32, 64x64x16 tile, 4x4 micro)
// ---------------------------------------------------------------------------
#define TM 64
#define TN 64
#define TK 16

__global__ __launch_bounds__(256) void gemm_bias_kernel(
    const float* __restrict__ A, const float* __restrict__ W,
    const float* __restrict__ bias, float* __restrict__ C) {
    __shared__ float As[TK][TM + 4];   // row stride 68 floats = 272B (16B-mult)
    __shared__ float Ws[TK][TN + 4];

    const int tid = threadIdx.x;
    const int tx = tid & 15;    // n micro index
    const int ty = tid >> 4;    // m micro index
    const int m0 = blockIdx.y * TM;
    const int n0 = blockIdx.x * TN;

    float acc[4][4] = {};

    const int kk_a = tid & 15;   // k index for A load
    const int mm_a = tid >> 4;   // 0..15
    const int nn_w = tid & 63;   // n index for W load
    const int kw_w = tid >> 6;   // 0..3

    for (int k0 = 0; k0 < HH; k0 += TK) {
#pragma unroll
        for (int i = 0; i < 4; ++i)
            As[kk_a][mm_a + i * 16] =
                A[(size_t)(m0 + mm_a + i * 16) * HH + k0 + kk_a];
#pragma unroll
        for (int i = 0; i < 4; ++i)
            Ws[kw_w + i * 4][nn_w] =
                W[(size_t)(k0 + kw_w + i * 4) * HH + n0 + nn_w];
        __syncthreads();

#pragma unroll
        for (int kk = 0; kk < TK; ++kk) {
            float4 a4 = *(const float4*)&As[kk][ty * 4];
            float4 b4 = *(const float4*)&Ws[kk][tx * 4];
            float a[4] = {a4.x, a4.y, a4.z, a4.w};
            float b[4] = {b4.x, b4.y, b4.z, b4.w};
#pragma unroll
            for (int i = 0; i < 4; ++i)
#pragma unroll
                for (int j = 0; j < 4; ++j)
                    acc[i][j] += a[i] * b[j];
        }
        __syncthreads();
    }

    float4 bia = *(const float4*)&bias[n0 + tx * 4];
    float bv[4] = {bia.x, bia.y, bia.z, bia.w};
#pragma unroll
    for (int i = 0; i < 4; ++i) {
        int m = m0 + ty * 4 + i;
        float4 o;
        o.x = acc[i][0] + bv[0];
        o.y = acc[i][1] + bv[1];
        o.z = acc[i][2] + bv[2];
        o.w = acc[i][3] + bv[3];
        *(float4*)&C[(size_t)m * HH + n0 + tx * 4] = o;
    }
}

// ---------------------------------------------------------------------------
// per-(b,l): scores over R=200 refs, softmax, scatter into zeroed [V] row
// ---------------------------------------------------------------------------
__global__ __launch_bounds__(256) void attn_scatter_kernel(
    const float* __restrict__ q,           // [B*L, H]
    const float* __restrict__ k,           // [B*R, H]
    const int* __restrict__ ids,           // [B*R]
    const unsigned char* __restrict__ last,// [B*R]
    float* __restrict__ out) {             // [B*L, V] (pre-zeroed)
    const int bl = blockIdx.x;             // 0..B*L-1
    const int b = bl / LL;
    const int tid = threadIdx.x;
    const int lane = tid & 63;
    const int wave = tid >> 6;             // 0..3

    __shared__ float qs[HH];
    __shared__ float sc[RR];
    __shared__ float red[8];

    for (int i = tid; i < HH; i += 256) qs[i] = q[(size_t)bl * HH + i];
    __syncthreads();

    const float scale = 0.036084391824351615f;  // 1/sqrt(768)

    for (int r = wave; r < RR; r += 4) {
        const float* kr = k + (size_t)(b * RR + r) * HH;
        float s = 0.f;
#pragma unroll
        for (int i = 0; i < HH / 64; ++i)
            s += qs[lane + i * 64] * kr[lane + i * 64];
#pragma unroll
        for (int off = 32; off > 0; off >>= 1)
            s += __shfl_xor(s, off);
        if (lane == 0) sc[r] = s * scale;
    }
    __syncthreads();

    float v = (tid < RR) ? sc[tid] : -INFINITY;
    float m = v;
#pragma unroll
    for (int off = 32; off > 0; off >>= 1)
        m = fmaxf(m, __shfl_xor(m, off));
    if (lane == 0) red[wave] = m;
    __syncthreads();
    m = fmaxf(fmaxf(red[0], red[1]), fmaxf(red[2], red[3]));

    float e = (tid < RR) ? __expf(v - m) : 0.f;
    float s = e;
#pragma unroll
    for (int off = 32; off > 0; off >>= 1)
        s += __shfl_xor(s, off);
    if (lane == 0) red[4 + wave] = s;
    __syncthreads();
    float inv = 1.0f / (red[4] + red[5] + red[6] + red[7]);

    if (tid < RR && last[b * RR + tid]) {
        out[(size_t)bl * VV + ids[b * RR + tid]] = e * inv;
    }
}

// ---------------------------------------------------------------------------
extern "C" void kernel_launch(void* const* d_in, const int* in_sizes, int n_in,
                              void* d_out, int out_size, void* d_ws, size_t ws_size,
                              hipStream_t stream) {
    const int*   ids    = (const int*)d_in[0];     // [B,R] int32
    const float* embeds = (const float*)d_in[1];   // [B,R,H]
    // d_in[2]: attention mask (all True) — masking is a no-op
    const float* hidden = (const float*)d_in[3];   // [B,L,H]
    // d_in[4]: vocab_size scalar — compile-time constant
    const float* Wq = (const float*)d_in[5];
    const float* bq = (const float*)d_in[6];
    const float* Wk = (const float*)d_in[7];
    const float* bk = (const float*)d_in[8];
    float* out = (float*)d_out;

    float* kbuf = (float*)d_ws;                          // [B*R, H]
    float* qbuf = kbuf + (size_t)BB * RR * HH;           // [B*L, H]
    unsigned char* flags = (unsigned char*)(qbuf + (size_t)BB * LL * HH);

    hipMemsetAsync(d_out, 0, (size_t)BB * LL * VV * sizeof(float), stream);

    last_occurrence_kernel<<<(BB * RR + 255) / 256, 256, 0, stream>>>(ids, flags);

    gemm_bias_kernel<<<dim3(HH / TN, (BB * RR) / TM), 256, 0, stream>>>(
        embeds, Wk, bk, kbuf);
    gemm_bias_kernel<<<dim3(HH / TN, (BB * LL) / TM), 256, 0, stream>>>(
        hidden, Wq, bq, qbuf);

    attn_scatter_kernel<<<BB * LL, 256, 0, stream>>>(qbuf, kbuf, ids, flags, out);
}

// Round 2
// 417.307 us; speedup vs baseline: 1.2068x; 1.2068x over previous
//
#include <hip/hip_runtime.h>
#include <math.h>

#define BB 16
#define LL 128
#define RR 200
#define HH 768
#define VV 30522

typedef __attribute__((ext_vector_type(8))) short short8;
typedef __attribute__((ext_vector_type(4))) float float4v;

__device__ __forceinline__ float b2f(unsigned short u) {
    union { unsigned int i; float f; } v; v.i = ((unsigned int)u) << 16; return v.f;
}
__device__ __forceinline__ unsigned short f2b(float f) {
    union { float f; unsigned int i; } v; v.f = f;
    return (unsigned short)((v.i + 0x7FFFu + ((v.i >> 16) & 1u)) >> 16);
}
__device__ __forceinline__ void b2f4(ushort4 h, float* o) {
    o[0] = b2f(h.x); o[1] = b2f(h.y); o[2] = b2f(h.z); o[3] = b2f(h.w);
}

// ---------------------------------------------------------------------------
// fp32 -> bf16 cast, 8 elements/thread
// ---------------------------------------------------------------------------
__global__ __launch_bounds__(256) void cast_bf16_kernel(
    const float* __restrict__ in, unsigned short* __restrict__ out, int n8) {
    int i = blockIdx.x * 256 + threadIdx.x;
    if (i >= n8) return;
    float4 x = ((const float4*)in)[i * 2];
    float4 y = ((const float4*)in)[i * 2 + 1];
    ushort4 lo = make_ushort4(f2b(x.x), f2b(x.y), f2b(x.z), f2b(x.w));
    ushort4 hi = make_ushort4(f2b(y.x), f2b(y.y), f2b(y.z), f2b(y.w));
    ((ushort4*)out)[i * 2] = lo;
    ((ushort4*)out)[i * 2 + 1] = hi;
}

// ---------------------------------------------------------------------------
// W [768k][768n] fp32 -> Wt [768n][768k] bf16 (32x32 LDS tiles)
// ---------------------------------------------------------------------------
__global__ __launch_bounds__(256) void transpose_cast_kernel(
    const float* __restrict__ W, unsigned short* __restrict__ Wt) {
    __shared__ unsigned short tile[32][36];
    const int r0 = blockIdx.y * 32, c0 = blockIdx.x * 32;
    const int row = threadIdx.x >> 3;
    const int c4 = (threadIdx.x & 7) * 4;
    float4 x = *(const float4*)&W[(size_t)(r0 + row) * HH + c0 + c4];
    tile[c4 + 0][row] = f2b(x.x);
    tile[c4 + 1][row] = f2b(x.y);
    tile[c4 + 2][row] = f2b(x.z);
    tile[c4 + 3][row] = f2b(x.w);
    __syncthreads();
    ushort4 o = make_ushort4(tile[row][c4], tile[row][c4 + 1],
                             tile[row][c4 + 2], tile[row][c4 + 3]);
    *(ushort4*)&Wt[(size_t)(c0 + row) * HH + r0 + c4] = o;
}

// ---------------------------------------------------------------------------
// last-occurrence flags (numpy fancy-assign: last write wins)
// ---------------------------------------------------------------------------
__global__ void last_occurrence_kernel(const int* __restrict__ ids,
                                       unsigned char* __restrict__ flag) {
    int i = blockIdx.x * 256 + threadIdx.x;
    if (i >= BB * RR) return;
    int b = i / RR;
    int r = i - b * RR;
    int id = ids[i];
    unsigned char ok = 1;
    for (int r2 = r + 1; r2 < RR; ++r2) {
        if (ids[b * RR + r2] == id) { ok = 0; break; }
    }
    flag[i] = ok;
}

// ---------------------------------------------------------------------------
// C[M][768] = A[M][768] @ W + bias, via Bt[n][k] bf16. MFMA 16x16x32.
// 128x128 tile, BK=32, 4 waves each computing 64x64.
// ---------------------------------------------------------------------------
__global__ __launch_bounds__(256) void gemm_bf16_kernel(
    const unsigned short* __restrict__ A,   // [M][768] bf16
    const unsigned short* __restrict__ Bt,  // [768n][768k] bf16
    const float* __restrict__ bias,         // [768]
    unsigned short* __restrict__ C)         // [M][768] bf16
{
    __shared__ unsigned short As[128][40];  // 80B row stride: conflict-free b128
    __shared__ unsigned short Bs[128][40];

    const int tid = threadIdx.x;
    const int lane = tid & 63;
    const int wave = tid >> 6;
    const int m0 = blockIdx.y * 128;
    const int n0 = blockIdx.x * 128;
    const int wm = (wave >> 1) * 64;
    const int wn = (wave & 1) * 64;
    const int l15 = lane & 15;
    const int kg = lane >> 4;

    float4v acc[4][4];
#pragma unroll
    for (int i = 0; i < 4; ++i)
#pragma unroll
        for (int j = 0; j < 4; ++j) acc[i][j] = (float4v){0.f, 0.f, 0.f, 0.f};

    const int r0 = tid >> 2;   // staging row 0..63 (i=1 adds 64)
    const int sg = tid & 3;    // k segment (8 bf16 = 16B each)

    for (int k0 = 0; k0 < HH; k0 += 32) {
        short8 a0 = *(const short8*)&A[(size_t)(m0 + r0) * HH + k0 + sg * 8];
        short8 a1 = *(const short8*)&A[(size_t)(m0 + r0 + 64) * HH + k0 + sg * 8];
        short8 b0 = *(const short8*)&Bt[(size_t)(n0 + r0) * HH + k0 + sg * 8];
        short8 b1 = *(const short8*)&Bt[(size_t)(n0 + r0 + 64) * HH + k0 + sg * 8];
        __syncthreads();   // previous iter's reads done before overwrite
        *(short8*)&As[r0][sg * 8] = a0;
        *(short8*)&As[r0 + 64][sg * 8] = a1;
        *(short8*)&Bs[r0][sg * 8] = b0;
        *(short8*)&Bs[r0 + 64][sg * 8] = b1;
        __syncthreads();

        short8 af[4], bf[4];
#pragma unroll
        for (int mi = 0; mi < 4; ++mi)
            af[mi] = *(const short8*)&As[wm + mi * 16 + l15][kg * 8];
#pragma unroll
        for (int ni = 0; ni < 4; ++ni)
            bf[ni] = *(const short8*)&Bs[wn + ni * 16 + l15][kg * 8];
#pragma unroll
        for (int mi = 0; mi < 4; ++mi)
#pragma unroll
            for (int ni = 0; ni < 4; ++ni)
                acc[mi][ni] = __builtin_amdgcn_mfma_f32_16x16x32_bf16(
                    af[mi], bf[ni], acc[mi][ni], 0, 0, 0);
    }

#pragma unroll
    for (int ni = 0; ni < 4; ++ni) {
        int col = n0 + wn + ni * 16 + l15;
        float bv = bias[col];
#pragma unroll
        for (int mi = 0; mi < 4; ++mi) {
            int rbase = m0 + wm + mi * 16 + kg * 4;
#pragma unroll
            for (int j = 0; j < 4; ++j)
                C[(size_t)(rbase + j) * HH + col] = f2b(acc[mi][ni][j] + bv);
        }
    }
}

// ---------------------------------------------------------------------------
// fused: zero vocab row + scores + softmax + scatter. 1 block per (b,l).
// ---------------------------------------------------------------------------
__global__ __launch_bounds__(256) void attn_fused_kernel(
    const unsigned short* __restrict__ q,   // [B*L][768] bf16
    const unsigned short* __restrict__ k,   // [B*R][768] bf16
    const int* __restrict__ ids,            // [B*R]
    const unsigned char* __restrict__ last, // [B*R]
    float* __restrict__ out)                // [B*L][V]
{
    const int bid = blockIdx.x;
    const int bl = ((bid & 7) << 8) | (bid >> 3);   // XCD-bijective swizzle
    const int b = bl >> 7;
    const int tid = threadIdx.x;
    const int lane = tid & 63;
    const int wave = tid >> 6;

    float* row_out = out + (size_t)bl * VV;

    // issue the 122 KB of zero stores first; compute overlaps their drain
    float2 z2 = make_float2(0.f, 0.f);
    for (int i = tid; i < VV / 2; i += 256)
        ((float2*)row_out)[i] = z2;

    __shared__ float sc[RR];
    __shared__ float red[8];

    // per-lane q fragment: 12 contiguous floats
    float qv[12];
    {
        const unsigned short* qr = q + (size_t)bl * HH + lane * 12;
        b2f4(*(const ushort4*)qr, qv);
        b2f4(*(const ushort4*)(qr + 4), qv + 4);
        b2f4(*(const ushort4*)(qr + 8), qv + 8);
    }

    const float scale = 0.036084391824351615f;  // 1/sqrt(768)

    for (int r = wave; r < RR; r += 4) {
        const unsigned short* kr = k + (size_t)(b * RR + r) * HH + lane * 12;
        float kv[12];
        b2f4(*(const ushort4*)kr, kv);
        b2f4(*(const ushort4*)(kr + 4), kv + 4);
        b2f4(*(const ushort4*)(kr + 8), kv + 8);
        float s = 0.f;
#pragma unroll
        for (int j = 0; j < 12; ++j) s += qv[j] * kv[j];
#pragma unroll
        for (int off = 32; off > 0; off >>= 1)
            s += __shfl_xor(s, off);
        if (lane == 0) sc[r] = s * scale;
    }
    __syncthreads();

    float v = (tid < RR) ? sc[tid] : -INFINITY;
    float m = v;
#pragma unroll
    for (int off = 32; off > 0; off >>= 1)
        m = fmaxf(m, __shfl_xor(m, off));
    if (lane == 0) red[wave] = m;
    __syncthreads();
    m = fmaxf(fmaxf(red[0], red[1]), fmaxf(red[2], red[3]));

    float e = (tid < RR) ? __expf(v - m) : 0.f;
    float s = e;
#pragma unroll
    for (int off = 32; off > 0; off >>= 1)
        s += __shfl_xor(s, off);
    if (lane == 0) red[4 + wave] = s;
    __syncthreads();
    float inv = 1.0f / (red[4] + red[5] + red[6] + red[7]);

    // barrier above guarantees zero stores drained before scatter overwrite
    if (tid < RR && last[b * RR + tid]) {
        row_out[ids[b * RR + tid]] = e * inv;
    }
}

// ---------------------------------------------------------------------------
extern "C" void kernel_launch(void* const* d_in, const int* in_sizes, int n_in,
                              void* d_out, int out_size, void* d_ws, size_t ws_size,
                              hipStream_t stream) {
    const int*   ids    = (const int*)d_in[0];
    const float* embeds = (const float*)d_in[1];
    const float* hidden = (const float*)d_in[3];
    const float* Wq = (const float*)d_in[5];
    const float* bq = (const float*)d_in[6];
    const float* Wk = (const float*)d_in[7];
    const float* bk = (const float*)d_in[8];
    float* out = (float*)d_out;

    unsigned short* hid_bf = (unsigned short*)d_ws;            // 2048*768
    unsigned short* emb_bf = hid_bf + (size_t)BB * LL * HH;    // 3200*768
    unsigned short* Wqt    = emb_bf + (size_t)BB * RR * HH;    // 768*768
    unsigned short* Wkt    = Wqt + (size_t)HH * HH;            // 768*768
    unsigned short* qbuf   = Wkt + (size_t)HH * HH;            // 2048*768
    unsigned short* kbuf   = qbuf + (size_t)BB * LL * HH;      // 3200*768
    unsigned char*  flags  = (unsigned char*)(kbuf + (size_t)BB * RR * HH);

    cast_bf16_kernel<<<768, 256, 0, stream>>>(hidden, hid_bf, BB * LL * HH / 8);
    cast_bf16_kernel<<<1200, 256, 0, stream>>>(embeds, emb_bf, BB * RR * HH / 8);
    transpose_cast_kernel<<<dim3(24, 24), 256, 0, stream>>>(Wq, Wqt);
    transpose_cast_kernel<<<dim3(24, 24), 256, 0, stream>>>(Wk, Wkt);
    last_occurrence_kernel<<<13, 256, 0, stream>>>(ids, flags);

    gemm_bf16_kernel<<<dim3(6, 16), 256, 0, stream>>>(hid_bf, Wqt, bq, qbuf);
    gemm_bf16_kernel<<<dim3(6, 25), 256, 0, stream>>>(emb_bf, Wkt, bk, kbuf);

    attn_fused_kernel<<<2048, 256, 0, stream>>>(qbuf, kbuf, ids, flags, out);
}

// Round 3
// 402.674 us; speedup vs baseline: 1.2507x; 1.0363x over previous
//
#include <hip/hip_runtime.h>
#include <math.h>

#define BB 16
#define LL 128
#define RR 200
#define HH 768
#define VV 30522

typedef __attribute__((ext_vector_type(8))) short short8;
typedef __attribute__((ext_vector_type(4))) float float4v;

__device__ __forceinline__ float b2f(unsigned short u) {
    union { unsigned int i; float f; } v; v.i = ((unsigned int)u) << 16; return v.f;
}
__device__ __forceinline__ unsigned short f2b(float f) {
    union { float f; unsigned int i; } v; v.f = f;
    return (unsigned short)((v.i + 0x7FFFu + ((v.i >> 16) & 1u)) >> 16);
}
__device__ __forceinline__ float u_lo(unsigned int u) {
    union { unsigned int i; float f; } v; v.i = u << 16; return v.f;
}
__device__ __forceinline__ float u_hi(unsigned int u) {
    union { unsigned int i; float f; } v; v.i = u & 0xFFFF0000u; return v.f;
}

// ---------------------------------------------------------------------------
// fp32 -> bf16 cast for BOTH input tensors in one launch (8 elems/thread)
// ---------------------------------------------------------------------------
__global__ __launch_bounds__(256) void cast_both_kernel(
    const float* __restrict__ a, const float* __restrict__ b,
    unsigned short* __restrict__ oa, unsigned short* __restrict__ ob,
    int n8a, int n8tot) {
    int i = blockIdx.x * 256 + threadIdx.x;
    if (i >= n8tot) return;
    const float* src = (i < n8a) ? a : b;
    unsigned short* dst = (i < n8a) ? oa : ob;
    int j = (i < n8a) ? i : i - n8a;
    float4 x = ((const float4*)src)[j * 2];
    float4 y = ((const float4*)src)[j * 2 + 1];
    ushort4 lo = make_ushort4(f2b(x.x), f2b(x.y), f2b(x.z), f2b(x.w));
    ushort4 hi = make_ushort4(f2b(y.x), f2b(y.y), f2b(y.z), f2b(y.w));
    ((ushort4*)dst)[j * 2] = lo;
    ((ushort4*)dst)[j * 2 + 1] = hi;
}

// ---------------------------------------------------------------------------
// W [768k][768n] fp32 -> Wt [768n][768k] bf16; z selects Wq/Wk
// ---------------------------------------------------------------------------
__global__ __launch_bounds__(256) void transpose_cast_kernel(
    const float* __restrict__ W0, unsigned short* __restrict__ Wt0,
    const float* __restrict__ W1, unsigned short* __restrict__ Wt1) {
    __shared__ unsigned short tile[32][36];
    const float* W = blockIdx.z ? W1 : W0;
    unsigned short* Wt = blockIdx.z ? Wt1 : Wt0;
    const int r0 = blockIdx.y * 32, c0 = blockIdx.x * 32;
    const int row = threadIdx.x >> 3;
    const int c4 = (threadIdx.x & 7) * 4;
    float4 x = *(const float4*)&W[(size_t)(r0 + row) * HH + c0 + c4];
    tile[c4 + 0][row] = f2b(x.x);
    tile[c4 + 1][row] = f2b(x.y);
    tile[c4 + 2][row] = f2b(x.z);
    tile[c4 + 3][row] = f2b(x.w);
    __syncthreads();
    ushort4 o = make_ushort4(tile[row][c4], tile[row][c4 + 1],
                             tile[row][c4 + 2], tile[row][c4 + 3]);
    *(ushort4*)&Wt[(size_t)(c0 + row) * HH + r0 + c4] = o;
}

// ---------------------------------------------------------------------------
// last-occurrence flags (numpy fancy-assign: last write wins)
// ---------------------------------------------------------------------------
__global__ void last_occurrence_kernel(const int* __restrict__ ids,
                                       unsigned char* __restrict__ flag) {
    int i = blockIdx.x * 256 + threadIdx.x;
    if (i >= BB * RR) return;
    int b = i / RR;
    int r = i - b * RR;
    int id = ids[i];
    unsigned char ok = 1;
    for (int r2 = r + 1; r2 < RR; ++r2) {
        if (ids[b * RR + r2] == id) { ok = 0; break; }
    }
    flag[i] = ok;
}

// ---------------------------------------------------------------------------
// C[M][768] = A[M][768] @ W + bias, via Bt[n][k] bf16. MFMA 16x16x32.
// 128x128 tile, BK=32, 4 waves each computing 64x64.
// ---------------------------------------------------------------------------
__global__ __launch_bounds__(256) void gemm_bf16_kernel(
    const unsigned short* __restrict__ A,   // [M][768] bf16
    const unsigned short* __restrict__ Bt,  // [768n][768k] bf16
    const float* __restrict__ bias,         // [768]
    unsigned short* __restrict__ C)         // [M][768] bf16
{
    __shared__ unsigned short As[128][40];  // 80B row stride
    __shared__ unsigned short Bs[128][40];

    const int tid = threadIdx.x;
    const int lane = tid & 63;
    const int wave = tid >> 6;
    const int m0 = blockIdx.y * 128;
    const int n0 = blockIdx.x * 128;
    const int wm = (wave >> 1) * 64;
    const int wn = (wave & 1) * 64;
    const int l15 = lane & 15;
    const int kg = lane >> 4;

    float4v acc[4][4];
#pragma unroll
    for (int i = 0; i < 4; ++i)
#pragma unroll
        for (int j = 0; j < 4; ++j) acc[i][j] = (float4v){0.f, 0.f, 0.f, 0.f};

    const int r0 = tid >> 2;
    const int sg = tid & 3;

    for (int k0 = 0; k0 < HH; k0 += 32) {
        short8 a0 = *(const short8*)&A[(size_t)(m0 + r0) * HH + k0 + sg * 8];
        short8 a1 = *(const short8*)&A[(size_t)(m0 + r0 + 64) * HH + k0 + sg * 8];
        short8 b0 = *(const short8*)&Bt[(size_t)(n0 + r0) * HH + k0 + sg * 8];
        short8 b1 = *(const short8*)&Bt[(size_t)(n0 + r0 + 64) * HH + k0 + sg * 8];
        __syncthreads();
        *(short8*)&As[r0][sg * 8] = a0;
        *(short8*)&As[r0 + 64][sg * 8] = a1;
        *(short8*)&Bs[r0][sg * 8] = b0;
        *(short8*)&Bs[r0 + 64][sg * 8] = b1;
        __syncthreads();

        short8 af[4], bf[4];
#pragma unroll
        for (int mi = 0; mi < 4; ++mi)
            af[mi] = *(const short8*)&As[wm + mi * 16 + l15][kg * 8];
#pragma unroll
        for (int ni = 0; ni < 4; ++ni)
            bf[ni] = *(const short8*)&Bs[wn + ni * 16 + l15][kg * 8];
#pragma unroll
        for (int mi = 0; mi < 4; ++mi)
#pragma unroll
            for (int ni = 0; ni < 4; ++ni)
                acc[mi][ni] = __builtin_amdgcn_mfma_f32_16x16x32_bf16(
                    af[mi], bf[ni], acc[mi][ni], 0, 0, 0);
    }

#pragma unroll
    for (int ni = 0; ni < 4; ++ni) {
        int col = n0 + wn + ni * 16 + l15;
        float bv = bias[col];
#pragma unroll
        for (int mi = 0; mi < 4; ++mi) {
            int rbase = m0 + wm + mi * 16 + kg * 4;
#pragma unroll
            for (int j = 0; j < 4; ++j)
                C[(size_t)(rbase + j) * HH + col] = f2b(acc[mi][ni][j] + bv);
        }
    }
}

// ---------------------------------------------------------------------------
// fused: zero vocab row + scores + softmax + scatter. 1 block per (b,l).
// k/q loads: 4B/lane contiguous (uint = bf16 pair) — coalescing fix.
// ---------------------------------------------------------------------------
__global__ __launch_bounds__(256) void attn_fused_kernel(
    const unsigned short* __restrict__ q,   // [B*L][768] bf16
    const unsigned short* __restrict__ k,   // [B*R][768] bf16
    const int* __restrict__ ids,            // [B*R]
    const unsigned char* __restrict__ last, // [B*R]
    float* __restrict__ out)                // [B*L][V]
{
    const int bid = blockIdx.x;
    const int bl = ((bid & 7) << 8) | (bid >> 3);   // XCD-bijective swizzle
    const int b = bl >> 7;
    const int tid = threadIdx.x;
    const int lane = tid & 63;
    const int wave = tid >> 6;

    float* row_out = out + (size_t)bl * VV;

    // issue the 122 KB of zero stores first; score compute overlaps the drain
    float2 z2 = make_float2(0.f, 0.f);
    for (int i = tid; i < VV / 2; i += 256)
        ((float2*)row_out)[i] = z2;

    __shared__ float sc[RR];
    __shared__ float red[8];

    // per-lane q fragment: 6 contiguous uints (12 bf16), 4B/lane coalesced
    float qf[12];
    {
        const unsigned int* qr = (const unsigned int*)(q + (size_t)bl * HH);
#pragma unroll
        for (int j = 0; j < 6; ++j) {
            unsigned int u = qr[lane + j * 64];
            qf[2 * j]     = u_lo(u);
            qf[2 * j + 1] = u_hi(u);
        }
    }

    const float scale = 0.036084391824351615f;  // 1/sqrt(768)

    for (int r = wave; r < RR; r += 4) {
        const unsigned int* kr =
            (const unsigned int*)(k + (size_t)(b * RR + r) * HH);
        float s = 0.f;
#pragma unroll
        for (int j = 0; j < 6; ++j) {
            unsigned int u = kr[lane + j * 64];
            s += qf[2 * j] * u_lo(u) + qf[2 * j + 1] * u_hi(u);
        }
#pragma unroll
        for (int off = 32; off > 0; off >>= 1)
            s += __shfl_xor(s, off);
        if (lane == 0) sc[r] = s * scale;
    }
    __syncthreads();

    float v = (tid < RR) ? sc[tid] : -INFINITY;
    float m = v;
#pragma unroll
    for (int off = 32; off > 0; off >>= 1)
        m = fmaxf(m, __shfl_xor(m, off));
    if (lane == 0) red[wave] = m;
    __syncthreads();
    m = fmaxf(fmaxf(red[0], red[1]), fmaxf(red[2], red[3]));

    float e = (tid < RR) ? __expf(v - m) : 0.f;
    float s = e;
#pragma unroll
    for (int off = 32; off > 0; off >>= 1)
        s += __shfl_xor(s, off);
    if (lane == 0) red[4 + wave] = s;
    __syncthreads();
    float inv = 1.0f / (red[4] + red[5] + red[6] + red[7]);

    // barriers above ordered the zero stores before this overwrite
    if (tid < RR && last[b * RR + tid]) {
        row_out[ids[b * RR + tid]] = e * inv;
    }
}

// ---------------------------------------------------------------------------
extern "C" void kernel_launch(void* const* d_in, const int* in_sizes, int n_in,
                              void* d_out, int out_size, void* d_ws, size_t ws_size,
                              hipStream_t stream) {
    const int*   ids    = (const int*)d_in[0];
    const float* embeds = (const float*)d_in[1];
    const float* hidden = (const float*)d_in[3];
    const float* Wq = (const float*)d_in[5];
    const float* bq = (const float*)d_in[6];
    const float* Wk = (const float*)d_in[7];
    const float* bk = (const float*)d_in[8];
    float* out = (float*)d_out;

    unsigned short* hid_bf = (unsigned short*)d_ws;            // 2048*768
    unsigned short* emb_bf = hid_bf + (size_t)BB * LL * HH;    // 3200*768
    unsigned short* Wqt    = emb_bf + (size_t)BB * RR * HH;    // 768*768
    unsigned short* Wkt    = Wqt + (size_t)HH * HH;            // 768*768
    unsigned short* qbuf   = Wkt + (size_t)HH * HH;            // 2048*768
    unsigned short* kbuf   = qbuf + (size_t)BB * LL * HH;      // 3200*768
    unsigned char*  flags  = (unsigned char*)(kbuf + (size_t)BB * RR * HH);

    const int n8h = BB * LL * HH / 8;           // 196608
    const int n8e = BB * RR * HH / 8;           // 307200
    cast_both_kernel<<<(n8h + n8e + 255) / 256, 256, 0, stream>>>(
        hidden, embeds, hid_bf, emb_bf, n8h, n8h + n8e);
    transpose_cast_kernel<<<dim3(24, 24, 2), 256, 0, stream>>>(Wq, Wqt, Wk, Wkt);
    last_occurrence_kernel<<<13, 256, 0, stream>>>(ids, flags);

    gemm_bf16_kernel<<<dim3(6, 16), 256, 0, stream>>>(hid_bf, Wqt, bq, qbuf);
    gemm_bf16_kernel<<<dim3(6, 25), 256, 0, stream>>>(emb_bf, Wkt, bk, kbuf);

    attn_fused_kernel<<<2048, 256, 0, stream>>>(qbuf, kbuf, ids, flags, out);
}